// Round 10
// baseline (47.382 us; speedup 1.0000x reference)
//
#include <hip/hip_runtime.h>

#define CELL_F 50            // floats per cell
#define LAMBDA_COORD 5.0f
#define LAMBDA_NOOBJ 0.5f
#define TILE_CELLS 64        // one tile = one wave's 64 cells
#define TILE_V4 800          // float4 per tensor per tile
#define NBLOCKS 1536         // 6 blocks/CU (25.6KB LDS each) * 256 CU

__device__ __forceinline__ float iou8(float ax, float ay, float aw, float ah,
                                      float bx, float by, float bw, float bh) {
    float w = fminf(ax + aw * 0.5f, bx + bw * 0.5f) - fmaxf(ax - aw * 0.5f, bx - bw * 0.5f);
    float h = fminf(ay + ah * 0.5f, by + bh * 0.5f) - fmaxf(ay - ah * 0.5f, by - bh * 0.5f);
    float cross = w * h;
    float denom = aw * ah + bw * bh - cross;
    float iou = cross / denom;
    return (w <= 0.0f || h <= 0.0f) ? 0.0f : iou;
}

// issue one tile's pr+gt loads (26 global_load_lds instrs, async, no waits)
__device__ __forceinline__ void issue_tile(const float4* __restrict__ pr4,
                                           const float4* __restrict__ gt4,
                                           int tile, float4* buf4, int lane) {
    const float4* ps = pr4 + (size_t)tile * TILE_V4;
    const float4* gs = gt4 + (size_t)tile * TILE_V4;
    char* A = (char*)buf4;                    // pr half: 12800 B
    char* B = (char*)(buf4 + TILE_V4);        // gt half: 12800 B
    #pragma unroll
    for (int r = 0; r < 12; ++r) {
        __builtin_amdgcn_global_load_lds(
            (const __attribute__((address_space(1))) void*)(ps + r * 64 + lane),
            (__attribute__((address_space(3))) void*)(A + r * 1024 + lane * 16),
            16, 0, 0);
    }
    if (lane < 32) {
        __builtin_amdgcn_global_load_lds(
            (const __attribute__((address_space(1))) void*)(ps + 768 + lane),
            (__attribute__((address_space(3))) void*)(A + 12288 + lane * 16),
            16, 0, 0);
    }
    #pragma unroll
    for (int r = 0; r < 12; ++r) {
        __builtin_amdgcn_global_load_lds(
            (const __attribute__((address_space(1))) void*)(gs + r * 64 + lane),
            (__attribute__((address_space(3))) void*)(B + r * 1024 + lane * 16),
            16, 0, 0);
    }
    if (lane < 32) {
        __builtin_amdgcn_global_load_lds(
            (const __attribute__((address_space(1))) void*)(gs + 768 + lane),
            (__attribute__((address_space(3))) void*)(B + 12288 + lane * 16),
            16, 0, 0);
    }
}

__global__ __launch_bounds__(64) void yolo_loss_fused(
        const float4* __restrict__ pr4, const float4* __restrict__ gt4,
        float* __restrict__ out, int ntiles, float inv_batch) {
    __shared__ float4 buf4[2 * TILE_V4];      // A:pr, B:gt = 25600 B
    float* bufA = reinterpret_cast<float*>(buf4);
    float* bufB = reinterpret_cast<float*>(buf4 + TILE_V4);
    const int lane = threadIdx.x;
    const int stride = gridDim.x;

    // prologue: first tile's 26 loads in flight
    issue_tile(pr4, gt4, blockIdx.x, buf4, lane);

    float acc = 0.0f;
    for (int tile = blockIdx.x; tile < ntiles; tile += stride) {
        asm volatile("s_waitcnt vmcnt(0)" ::: "memory");   // tile's loads landed
        __builtin_amdgcn_sched_barrier(0);

        // unpack this lane's cell from both buffers
        float P[CELL_F], G[CELL_F];
        {
            const float* sp = bufA + lane * CELL_F;        // 200B stride, 8B aligned
            const float* sg = bufB + lane * CELL_F;
            #pragma unroll
            for (int i = 0; i < CELL_F / 2; ++i) {
                float2 v = *reinterpret_cast<const float2*>(sp + 2 * i);
                P[2 * i] = v.x; P[2 * i + 1] = v.y;
                float2 u = *reinterpret_cast<const float2*>(sg + 2 * i);
                G[2 * i] = u.x; G[2 * i + 1] = u.y;
            }
        }
        asm volatile("s_waitcnt lgkmcnt(0)" ::: "memory"); // reads done; buf free
        __builtin_amdgcn_sched_barrier(0);

        // prefetch next tile: its HBM latency hides under compute below
        int next = tile + stride;
        if (next < ntiles) issue_tile(pr4, gt4, next, buf4, lane);

        // ---- per-cell YOLOv1 loss ----
        float gc0 = G[0], gc1 = G[25];
        int obj_num = (gc0 != 0.0f ? 1 : 0) + (gc1 != 0.0f ? 1 : 0);
        float pc0 = P[0], pc1 = P[25];

        if (obj_num == 0) {
            acc += LAMBDA_NOOBJ * (pc0 + pc1);
        } else {
            float c0 = pc0 - 1.0f, c1 = pc1 - 1.0f;
            acc += c0 * c0 + c1 * c1;

            float iou00 = iou8(P[21], P[22], P[23], P[24], G[21], G[22], G[23], G[24]);
            float iou01 = iou8(P[21], P[22], P[23], P[24], G[46], G[47], G[48], G[49]);
            float iou10 = iou8(P[46], P[47], P[48], P[49], G[21], G[22], G[23], G[24]);
            float iou11 = iou8(P[46], P[47], P[48], P[49], G[46], G[47], G[48], G[49]);

            bool v1 = (obj_num > 1);
            float m01 = v1 ? iou01 : -1.0f;
            float m11 = v1 ? iou11 : -1.0f;
            int rsp0 = (m01 > iou00) ? 1 : 0;   // first-max argmax
            int rsp1 = (m11 > iou10) ? 1 : 0;

            float s00 = 0.0f, s01 = 0.0f, s10 = 0.0f, s11 = 0.0f;
            #pragma unroll
            for (int k = 0; k < 20; ++k) {
                float pk0 = P[1 + k], pk1 = P[26 + k];
                float gk0 = G[1 + k], gk1 = G[26 + k];
                float d;
                d = pk0 - gk0; s00 += d * d;
                d = pk0 - gk1; s01 += d * d;
                d = pk1 - gk0; s10 += d * d;
                d = pk1 - gk1; s11 += d * d;
            }
            float cls0 = (rsp0 ? s01 : s00) * (1.0f / 20.0f);
            float cls1 = (rsp1 ? s11 : s10) * (1.0f / 20.0f);

            {
                float rx = rsp0 ? G[46] : G[21];
                float ry = rsp0 ? G[47] : G[22];
                float rw = rsp0 ? G[48] : G[23];
                float rh = rsp0 ? G[49] : G[24];
                float dx = P[21] - rx, dy = P[22] - ry;
                float dw = sqrtf(P[23]) - sqrtf(rw);
                float dh = sqrtf(P[24]) - sqrtf(rh);
                acc += LAMBDA_COORD * (dx * dx + dy * dy + dw * dw + dh * dh) + cls0;
            }
            {
                float rx = rsp1 ? G[46] : G[21];
                float ry = rsp1 ? G[47] : G[22];
                float rw = rsp1 ? G[48] : G[23];
                float rh = rsp1 ? G[49] : G[24];
                float dx = P[46] - rx, dy = P[47] - ry;
                float dw = sqrtf(P[48]) - sqrtf(rw);
                float dh = sqrtf(P[49]) - sqrtf(rh);
                acc += LAMBDA_COORD * (dx * dx + dy * dy + dw * dw + dh * dh) + cls1;
            }
        }
    }

    // wave reduction; one pre-scaled atomic per block into d_out[0]
    #pragma unroll
    for (int off = 32; off > 0; off >>= 1) acc += __shfl_down(acc, off);
    if (lane == 0) {
        unsafeAtomicAdd(out, acc * inv_batch);   // HW global_atomic_add_f32
    }
}

extern "C" void kernel_launch(void* const* d_in, const int* in_sizes, int n_in,
                              void* d_out, int out_size, void* d_ws, size_t ws_size,
                              hipStream_t stream) {
    const float4* pr4 = (const float4*)d_in[0];
    const float4* gt4 = (const float4*)d_in[1];
    float* out = (float*)d_out;

    int total_elems = in_sizes[0];            // 20,070,400
    int ncells = total_elems / CELL_F;        // 401,408
    int batch = total_elems / 2450;           // 8192
    int ntiles = ncells / TILE_CELLS;         // 6272

    // accumulator must start at 0 every call (harness does not re-poison)
    hipMemsetAsync(d_out, 0, sizeof(float), stream);

    int blocks = NBLOCKS < ntiles ? NBLOCKS : ntiles;
    yolo_loss_fused<<<blocks, 64, 0, stream>>>(pr4, gt4, out, ntiles, 1.0f / (float)batch);
}

// Round 11
// 31.917 us; speedup vs baseline: 1.4845x; 1.4845x over previous
//
#include <hip/hip_runtime.h>

#define CELL_F 50            // floats per cell
#define LAMBDA_COORD 5.0f
#define LAMBDA_NOOBJ 0.5f
#define TILE_CELLS 64        // one tile = one wave's 64 cells
#define TILE_V4 800          // float4 per tensor per tile
#define NBLOCKS 1536         // 6 blocks/CU (25.6KB LDS each) * 256 CU, all resident

__device__ __forceinline__ float iou8(float ax, float ay, float aw, float ah,
                                      float bx, float by, float bw, float bh) {
    float w = fminf(ax + aw * 0.5f, bx + bw * 0.5f) - fmaxf(ax - aw * 0.5f, bx - bw * 0.5f);
    float h = fminf(ay + ah * 0.5f, by + bh * 0.5f) - fmaxf(ay - ah * 0.5f, by - bh * 0.5f);
    float cross = w * h;
    float denom = aw * ah + bw * bh - cross;
    float iou = cross / denom;
    return (w <= 0.0f || h <= 0.0f) ? 0.0f : iou;
}

// issue one tensor's 13 loads for a tile (async global->LDS, 1KB per instr)
__device__ __forceinline__ void issue_half(const float4* __restrict__ src,
                                           char* dst, int lane) {
    #pragma unroll
    for (int r = 0; r < 12; ++r) {
        __builtin_amdgcn_global_load_lds(
            (const __attribute__((address_space(1))) void*)(src + r * 64 + lane),
            (__attribute__((address_space(3))) void*)(dst + r * 1024 + lane * 16),
            16, 0, 0);
    }
    if (lane < 32) {
        __builtin_amdgcn_global_load_lds(
            (const __attribute__((address_space(1))) void*)(src + 768 + lane),
            (__attribute__((address_space(3))) void*)(dst + 12288 + lane * 16),
            16, 0, 0);
    }
}

__global__ __launch_bounds__(64) void yolo_loss_partial(
        const float4* __restrict__ pr4, const float4* __restrict__ gt4,
        float* __restrict__ partial, int ntiles) {
    __shared__ float4 buf4[2 * TILE_V4];      // A:pr, B:gt = 25600 B
    float* bufA = reinterpret_cast<float*>(buf4);
    float* bufB = reinterpret_cast<float*>(buf4 + TILE_V4);
    const int lane = threadIdx.x;
    const int stride = gridDim.x;

    // prologue: first tile's 26 loads in flight (pr first, then gt)
    issue_half(pr4 + (size_t)blockIdx.x * TILE_V4, (char*)buf4, lane);
    issue_half(gt4 + (size_t)blockIdx.x * TILE_V4, (char*)(buf4 + TILE_V4), lane);

    float acc = 0.0f;
    for (int tile = blockIdx.x; tile < ntiles; tile += stride) {
        // pr's 13 loads are the oldest 13 outstanding -> vmcnt(13) = pr landed
        asm volatile("s_waitcnt vmcnt(13)" ::: "memory");
        __builtin_amdgcn_sched_barrier(0);

        // unpack pr while gt's 13 loads are still in flight
        float P[CELL_F], G[CELL_F];
        {
            const float* sp = bufA + lane * CELL_F;        // 200B stride, 8B aligned
            #pragma unroll
            for (int i = 0; i < CELL_F / 2; ++i) {
                float2 v = *reinterpret_cast<const float2*>(sp + 2 * i);
                P[2 * i] = v.x; P[2 * i + 1] = v.y;
            }
        }
        asm volatile("s_waitcnt vmcnt(0)" ::: "memory");   // gt landed
        __builtin_amdgcn_sched_barrier(0);
        {
            const float* sg = bufB + lane * CELL_F;
            #pragma unroll
            for (int i = 0; i < CELL_F / 2; ++i) {
                float2 u = *reinterpret_cast<const float2*>(sg + 2 * i);
                G[2 * i] = u.x; G[2 * i + 1] = u.y;
            }
        }
        asm volatile("s_waitcnt lgkmcnt(0)" ::: "memory"); // all ds_reads done; bufs free
        __builtin_amdgcn_sched_barrier(0);

        // prefetch next tile: HBM latency hides under compute below
        int next = tile + stride;
        if (next < ntiles) {
            issue_half(pr4 + (size_t)next * TILE_V4, (char*)buf4, lane);
            issue_half(gt4 + (size_t)next * TILE_V4, (char*)(buf4 + TILE_V4), lane);
        }

        // ---- per-cell YOLOv1 loss ----
        float gc0 = G[0], gc1 = G[25];
        int obj_num = (gc0 != 0.0f ? 1 : 0) + (gc1 != 0.0f ? 1 : 0);
        float pc0 = P[0], pc1 = P[25];

        if (obj_num == 0) {
            acc += LAMBDA_NOOBJ * (pc0 + pc1);
        } else {
            float c0 = pc0 - 1.0f, c1 = pc1 - 1.0f;
            acc += c0 * c0 + c1 * c1;

            float iou00 = iou8(P[21], P[22], P[23], P[24], G[21], G[22], G[23], G[24]);
            float iou01 = iou8(P[21], P[22], P[23], P[24], G[46], G[47], G[48], G[49]);
            float iou10 = iou8(P[46], P[47], P[48], P[49], G[21], G[22], G[23], G[24]);
            float iou11 = iou8(P[46], P[47], P[48], P[49], G[46], G[47], G[48], G[49]);

            bool v1 = (obj_num > 1);
            float m01 = v1 ? iou01 : -1.0f;
            float m11 = v1 ? iou11 : -1.0f;
            int rsp0 = (m01 > iou00) ? 1 : 0;   // first-max argmax
            int rsp1 = (m11 > iou10) ? 1 : 0;

            float s00 = 0.0f, s01 = 0.0f, s10 = 0.0f, s11 = 0.0f;
            #pragma unroll
            for (int k = 0; k < 20; ++k) {
                float pk0 = P[1 + k], pk1 = P[26 + k];
                float gk0 = G[1 + k], gk1 = G[26 + k];
                float d;
                d = pk0 - gk0; s00 += d * d;
                d = pk0 - gk1; s01 += d * d;
                d = pk1 - gk0; s10 += d * d;
                d = pk1 - gk1; s11 += d * d;
            }
            float cls0 = (rsp0 ? s01 : s00) * (1.0f / 20.0f);
            float cls1 = (rsp1 ? s11 : s10) * (1.0f / 20.0f);

            {
                float rx = rsp0 ? G[46] : G[21];
                float ry = rsp0 ? G[47] : G[22];
                float rw = rsp0 ? G[48] : G[23];
                float rh = rsp0 ? G[49] : G[24];
                float dx = P[21] - rx, dy = P[22] - ry;
                float dw = sqrtf(P[23]) - sqrtf(rw);
                float dh = sqrtf(P[24]) - sqrtf(rh);
                acc += LAMBDA_COORD * (dx * dx + dy * dy + dw * dw + dh * dh) + cls0;
            }
            {
                float rx = rsp1 ? G[46] : G[21];
                float ry = rsp1 ? G[47] : G[22];
                float rw = rsp1 ? G[48] : G[23];
                float rh = rsp1 ? G[49] : G[24];
                float dx = P[46] - rx, dy = P[47] - ry;
                float dw = sqrtf(P[48]) - sqrtf(rw);
                float dh = sqrtf(P[49]) - sqrtf(rh);
                acc += LAMBDA_COORD * (dx * dx + dy * dy + dw * dw + dh * dh) + cls1;
            }
        }
    }

    // wave reduction; one plain partial store per block (no atomics!)
    #pragma unroll
    for (int off = 32; off > 0; off >>= 1) acc += __shfl_down(acc, off);
    if (lane == 0) partial[blockIdx.x] = acc;
}

__global__ __launch_bounds__(256) void yolo_loss_final(
        const float4* __restrict__ partial4, int n4, float* __restrict__ out,
        float inv_batch) {
    float acc = 0.0f;
    for (int i = threadIdx.x; i < n4; i += 256) {
        float4 v = partial4[i];
        acc += (v.x + v.y) + (v.z + v.w);
    }
    #pragma unroll
    for (int off = 32; off > 0; off >>= 1) acc += __shfl_down(acc, off);
    __shared__ float wsum[4];
    int lane = threadIdx.x & 63;
    int wid = threadIdx.x >> 6;
    if (lane == 0) wsum[wid] = acc;
    __syncthreads();
    if (threadIdx.x == 0) {
        out[0] = (wsum[0] + wsum[1] + wsum[2] + wsum[3]) * inv_batch;
    }
}

extern "C" void kernel_launch(void* const* d_in, const int* in_sizes, int n_in,
                              void* d_out, int out_size, void* d_ws, size_t ws_size,
                              hipStream_t stream) {
    const float4* pr4 = (const float4*)d_in[0];
    const float4* gt4 = (const float4*)d_in[1];
    float* out = (float*)d_out;
    float* partial = (float*)d_ws;

    int total_elems = in_sizes[0];            // 20,070,400
    int ncells = total_elems / CELL_F;        // 401,408
    int batch = total_elems / 2450;           // 8192
    int ntiles = ncells / TILE_CELLS;         // 6272

    int blocks = NBLOCKS < ntiles ? NBLOCKS : ntiles;   // 1536, divisible by 4
    yolo_loss_partial<<<blocks, 64, 0, stream>>>(pr4, gt4, partial, ntiles);
    yolo_loss_final<<<1, 256, 0, stream>>>((const float4*)partial, blocks / 4, out,
                                           1.0f / (float)batch);
}